// Round 9
// baseline (149.724 us; speedup 1.0000x reference)
//
#include <hip/hip_runtime.h>
#include <math.h>

#define Bn    4
#define HIDc  64          // hidden / input channels each = 64
#define INCc  128         // concat channels
#define OUTCc 256         // 4*HID gates
#define Dd    256         // meta dim
#define NT    9           // K*K taps
#define HWn   4096        // 64*64
#define NC    18          // K=1152 in 64-chunks, k = n*128 + c

typedef _Float16 f16;
typedef unsigned short u16;
typedef unsigned int u32;
typedef __attribute__((ext_vector_type(8))) _Float16 h8;   // 8 fp16 (4 VGPRs)
typedef __attribute__((ext_vector_type(4))) _Float16 h4;   // 4 fp16 (8B)
typedef __attribute__((ext_vector_type(4))) float f4;      // MFMA C/D frag

// ---- workspace layout ----
// floats: bm [B][OUTC] = 1024 floats at offset 0
// f16 region (elem offsets from byte 4096):
//   TX  [B][4096 pos][128 ch]                     2,097,152
//   WH  [B][18 kc][256 rr][8 slot][8 e]           1,179,648  (granule-swizzled)
//   M1H [B][128 c][256 d], M1L same                 131,072 each
#define F16_BYTE 4096
#define TX_F   ((size_t)0)
#define WH_F   ((size_t)2097152)
#define M1H_F  ((size_t)3276800)
#define M1L_F  ((size_t)3407872)

__device__ __forceinline__ float sigf(float x) { return 1.f / (1.f + __expf(-x)); }
__device__ __forceinline__ float tanhfast(float x) {
    float a = fabsf(x);
    float e = __expf(2.f * a);
    float t = 1.f - 2.f / (e + 1.f);
    return copysignf(t, x);
}

// ---------------------------------------------------------------------------
// Kernel 0 (fused): blocks 0..255  = k_tr   (channel-last fp16 copy of x||h)
//                   blocks 256..771 = k_hyper (wm1 rows -> fp16 hi/lo, bl -> bm)
// ---------------------------------------------------------------------------
__global__ void __launch_bounds__(256)
k_prep(const float* __restrict__ xin, const float* __restrict__ hcur,
       f16* __restrict__ tx, const float* __restrict__ meta,
       const float* __restrict__ w1w, const float* __restrict__ w1b,
       const float* __restrict__ blw, const float* __restrict__ blb,
       float* __restrict__ bm, f16* __restrict__ m1h, f16* __restrict__ m1l)
{
    __shared__ __align__(16) float sm[Bn * Dd];
    int t = threadIdx.x;
    int bid = blockIdx.x;

    if (bid < 256) {                          // ---- k_tr path ----
        int b = bid >> 6, h = bid & 63;
        int w = t & 63, oq = t >> 6;          // oq 0..3
        const float* xb = xin  + ((size_t)b * HIDc) * HWn + h * 64;
        const float* hb = hcur + ((size_t)b * HIDc) * HWn + h * 64;
        f16* dst = tx + ((size_t)(b * HWn + h * 64 + w)) * INCc;
#pragma unroll
        for (int s = 0; s < 4; s++) {
            int c0 = (oq + s * 4) * 8;        // 0..120
            h8 v;
#pragma unroll
            for (int i = 0; i < 8; i++) {
                int ci = c0 + i;
                float f = (ci < HIDc) ? xb[(size_t)ci * HWn + w]
                                      : hb[(size_t)(ci - HIDc) * HWn + w];
                v[i] = (f16)f;
            }
            *(h8*)(dst + c0) = v;
        }
        return;
    }

    // ---- k_hyper path ----
    int hbid = bid - 256;                     // 0..515
    for (int i = t; i < Bn * Dd; i += 256) sm[i] = meta[i];
    __syncthreads();

    int lane = t & 63, wvv = t >> 6;
    int rl = lane >> 4, dl = lane & 15;
    int rbase = hbid * 64 + wvv * 16;

#pragma unroll
    for (int g = 0; g < 4; g++) {
        int r = rbase + g * 4 + rl;
        bool isbl = (r >= INCc * Dd);
        const float* row = isbl ? (blw + (size_t)(r - INCc * Dd) * Dd)
                                : (w1w + (size_t)r * Dd);
        float a0 = 0.f, a1 = 0.f, a2 = 0.f, a3 = 0.f;
#pragma unroll
        for (int it = 0; it < 4; it++) {
            int d = it * 64 + dl * 4;
            float4 wv = *(const float4*)(row + d);
            float4 m0 = *(const float4*)&sm[0 * Dd + d];
            float4 m1 = *(const float4*)&sm[1 * Dd + d];
            float4 m2 = *(const float4*)&sm[2 * Dd + d];
            float4 m3 = *(const float4*)&sm[3 * Dd + d];
            a0 += wv.x*m0.x + wv.y*m0.y + wv.z*m0.z + wv.w*m0.w;
            a1 += wv.x*m1.x + wv.y*m1.y + wv.z*m1.z + wv.w*m1.w;
            a2 += wv.x*m2.x + wv.y*m2.y + wv.z*m2.z + wv.w*m2.w;
            a3 += wv.x*m3.x + wv.y*m3.y + wv.z*m3.z + wv.w*m3.w;
        }
#pragma unroll
        for (int mk = 1; mk <= 8; mk <<= 1) {
            a0 += __shfl_xor(a0, mk); a1 += __shfl_xor(a1, mk);
            a2 += __shfl_xor(a2, mk); a3 += __shfl_xor(a3, mk);
        }
        if (dl == 0) {
            if (isbl) {
                int rb = r - INCc * Dd;
                float bb = blb[rb];
                bm[0*OUTCc + rb] = a0 + bb;
                bm[1*OUTCc + rb] = a1 + bb;
                bm[2*OUTCc + rb] = a2 + bb;
                bm[3*OUTCc + rb] = a3 + bb;
            } else {
                float bb = w1b[r];
                float v[4] = {a0 + bb, a1 + bb, a2 + bb, a3 + bb};
#pragma unroll
                for (int bi = 0; bi < 4; bi++) {
                    f16 hi = (f16)v[bi];
                    f16 lo = (f16)(v[bi] - (float)hi);
                    m1h[(size_t)bi * 32768 + r] = hi;
                    m1l[(size_t)bi * 32768 + r] = lo;
                }
            }
        }
    }
}

// ---------------------------------------------------------------------------
// Kernel 2: per-sample hyper GEMM via fp16 MFMA, A = wm1 (hi/lo split),
// B = w2_w (fp16 RN, converted during staging). K=256 fully LDS-resident,
// ONE barrier. Tile 32c x 64j, 576 blocks. Stride-256 rows + granule-XOR
// swizzle (g -> g^(row&7)), 64 KB LDS. Epilogue: 4 consecutive kk per (cf)
// share one WH granule -> packed 8B stores.
// ---------------------------------------------------------------------------
__global__ void __launch_bounds__(256)
k_w2(const float* __restrict__ w2w, const float* __restrict__ w2b,
     const f16* __restrict__ m1h, const f16* __restrict__ m1l,
     f16* __restrict__ wh)
{
    int bid = blockIdx.x;
    int b   = bid / 144;
    int rem = bid % 144;
    int c0  = (rem / 36) * 32;
    int j0  = (rem % 36) * 64;

    __shared__ __align__(16) f16 Ah[32][256];   // granule-XOR swizzled
    __shared__ __align__(16) f16 Al[32][256];
    __shared__ __align__(16) f16 Bh[64][256];

    int t = threadIdx.x;
    {   // stage A (hi/lo): row 0..31, seg 0..7 -> granules seg*4+i (i<4)
        int row = t >> 3, seg = t & 7;
        const f16* sh = m1h + (size_t)b * 32768 + (size_t)(c0 + row) * 256 + seg * 32;
        const f16* sl = m1l + (size_t)b * 32768 + (size_t)(c0 + row) * 256 + seg * 32;
#pragma unroll
        for (int i = 0; i < 4; i++) {
            int gsl = ((seg * 4 + i) ^ (row & 7)) * 8;
            *(h8*)&Ah[row][gsl] = *(const h8*)(sh + i * 8);
            *(h8*)&Al[row][gsl] = *(const h8*)(sl + i * 8);
        }
        // stage B (fp32 -> fp16 convert): row2 0..63, seg2 0..3 -> granules seg2*8+i
        int row2 = t >> 2, seg2 = t & 3;
        const float* sb = w2w + (size_t)(j0 + row2) * 256 + seg2 * 64;
#pragma unroll
        for (int i = 0; i < 8; i++) {
            float4 x0 = *(const float4*)(sb + i * 8);
            float4 x1 = *(const float4*)(sb + i * 8 + 4);
            h8 v = {(f16)x0.x, (f16)x0.y, (f16)x0.z, (f16)x0.w,
                    (f16)x1.x, (f16)x1.y, (f16)x1.z, (f16)x1.w};
            *(h8*)&Bh[row2][((seg2 * 8 + i) ^ (row2 & 7)) * 8] = v;
        }
    }
    __syncthreads();

    int lane = t & 63, jw = t >> 6;
    int col = lane & 15, quad = lane >> 4;

    f4 acc[2];
    acc[0] = (f4){0.f, 0.f, 0.f, 0.f};
    acc[1] = (f4){0.f, 0.f, 0.f, 0.f};
#pragma unroll
    for (int ks = 0; ks < 8; ks++) {
        int gsl = ((ks * 4 + quad) ^ (col & 7)) * 8;
        h8 Bf = *(const h8*)&Bh[jw * 16 + col][gsl];
#pragma unroll
        for (int cf = 0; cf < 2; cf++) {
            h8 Ahf = *(const h8*)&Ah[cf * 16 + col][gsl];
            h8 Alf = *(const h8*)&Al[cf * 16 + col][gsl];
            acc[cf] = __builtin_amdgcn_mfma_f32_16x16x32_f16(Ahf, Bf, acc[cf], 0, 0, 0);
            acc[cf] = __builtin_amdgcn_mfma_f32_16x16x32_f16(Alf, Bf, acc[cf], 0, 0, 0);
        }
    }

    int j = j0 + jw * 16 + col;
    int o = j / 9, n = j - o * 9;
    float bias = w2b[j];
    int rr = ((o & 63) << 2) | (o >> 6);
    f16* whb = wh + (size_t)b * (NC * 16384);
#pragma unroll
    for (int cf = 0; cf < 2; cf++) {
        int cbase = c0 + cf * 16 + quad * 4;      // multiple of 4
        int k0  = n * 128 + cbase;
        int kc  = k0 >> 6, kk0 = k0 & 63;         // kk0 % 4 == 0
        int slot = (kk0 >> 3) ^ (rr & 7);
        h4 pk;
#pragma unroll
        for (int rg = 0; rg < 4; rg++) pk[rg] = (f16)(acc[cf][rg] + bias);
        *(h4*)&whb[((size_t)kc * 256 + rr) * 64 + slot * 8 + (kk0 & 7)] = pk;
    }
}

// ---------------------------------------------------------------------------
// Kernel 3: R8's two-barrier single-buffer structure, with the gather
// GLOBAL LOADS hoisted above barrier1 (read-only TX -> no ordering hazard;
// results held in regs). The Xs ds_write (commit) stays after the MFMAs,
// i.e. after barrier1 (write-after-all-reads) and before barrier2
// (visibility) — identical memory ordering to R8.
// (R7's single-barrier double-buffer variant raced on warm replays — do
//  not re-land without an asm-level audit.)
// ---------------------------------------------------------------------------
__global__ void __launch_bounds__(512)
k_main(const f16* __restrict__ tx, const float* __restrict__ ccur,
       const float* __restrict__ moff, const float* __restrict__ pw,
       const float* __restrict__ pb, const float* __restrict__ bm,
       const f16* __restrict__ wh, float* __restrict__ out)
{
    int bid = blockIdx.x;
    int xcd = bid & 7;
    int b   = xcd >> 1;                       // 2 XCD slots per sample
    int h   = ((bid >> 3) << 1) | (xcd & 1);  // 0..63

    __shared__ u16   sIdx[NT][4][64];
    __shared__ float sWgt[NT][4][64];
    __shared__ __align__(16) f16 Wb[256 * 64];   // 32 KB, granule-swizzled
    __shared__ __align__(16) f16 Xs[64][64];     // 8 KB, granule-swizzled
    __shared__ float bmS[OUTCc];

    int t = threadIdx.x;
    if (t < 256) bmS[t] = bm[b * OUTCc + t];

    // ---- phase 0: offset conv + bilinear tables for 64 px x 9 taps ----
    {
        int px = t & 63;
        int nh = t >> 6;                      // 0..7
        for (int n = nh; n < NT; n += 8) {
            float ox = pb[n], oy = pb[NT + n];
#pragma unroll
            for (int ii = 0; ii < 3; ii++) {
#pragma unroll
                for (int jj = 0; jj < 3; jj++) {
                    int rr = h - 1 + ii, cc = px - 1 + jj;
                    float m = (rr >= 0 && rr < 64 && cc >= 0 && cc < 64)
                              ? moff[(size_t)b * HWn + rr * 64 + cc] : 0.f;
                    ox = fmaf(pw[(size_t)n * 9 + ii * 3 + jj], m, ox);
                    oy = fmaf(pw[(size_t)(NT + n) * 9 + ii * 3 + jj], m, oy);
                }
            }
            float pr = (float)(h + (n / 3)) + ox;
            float pc = (float)(px + (n % 3)) + oy;
            float fr = floorf(pr), fc = floorf(pc);
            float ltr = fminf(fmaxf(fr, 0.f), 65.f);
            float ltc = fminf(fmaxf(fc, 0.f), 65.f);
            float rbr = fminf(fmaxf(fr + 1.f, 0.f), 65.f);
            float rbc = fminf(fmaxf(fc + 1.f, 0.f), 65.f);
            float cpr = fminf(fmaxf(pr, 0.f), 65.f);
            float cpc = fminf(fmaxf(pc, 0.f), 65.f);
            float ar = 1.f + ltr - cpr, br = 1.f - rbr + cpr;
            float ac = 1.f + ltc - cpc, bc = 1.f - rbc + cpc;
            int ir0 = (int)ltr, ic0 = (int)ltc, ir1 = (int)rbr, ic1 = (int)rbc;
            int   rr4[4] = {ir0, ir1, ir0, ir1};
            int   cc4[4] = {ic0, ic1, ic1, ic0};
            float gg4[4] = {ar * ac, br * bc, ar * bc, br * ac};
#pragma unroll
            for (int jj = 0; jj < 4; jj++) {
                bool inb = (rr4[jj] >= 1) && (rr4[jj] <= 64) &&
                           (cc4[jj] >= 1) && (cc4[jj] <= 64);
                sIdx[n][jj][px] = (u16)(inb ? ((rr4[jj] - 1) * 64 + (cc4[jj] - 1)) : 0);
                sWgt[n][jj][px] = inb ? gg4[jj] : 0.f;
            }
        }
    }
    __syncthreads();

    int lane  = t & 63;
    int wv    = t >> 6;          // wave 0..7
    int col   = lane & 15, quad = lane >> 4;
    int ow    = wv & 3;          // o 64-range
    int ph    = wv >> 2;         // px half (0/1)
    int sp_px = t >> 3;          // sampling pixel 0..63
    int sp_oc = t & 7;           // sampling channel octet

    const f16* txb = tx + (size_t)b * HWn * INCc;
    const f16* whb = wh + (size_t)b * (NC * 16384);

    auto gather = [&](int KC, h8* v) {
        int n_ = KC >> 1;
        int co = ((KC & 1) << 6) + sp_oc * 8;
        v[0] = *(const h8*)(txb + (size_t)sIdx[n_][0][sp_px] * INCc + co);
        v[1] = *(const h8*)(txb + (size_t)sIdx[n_][1][sp_px] * INCc + co);
        v[2] = *(const h8*)(txb + (size_t)sIdx[n_][2][sp_px] * INCc + co);
        v[3] = *(const h8*)(txb + (size_t)sIdx[n_][3][sp_px] * INCc + co);
    };
    auto commit = [&](int KC, const h8* v) {
        int n_ = KC >> 1;
        float g0 = sWgt[n_][0][sp_px], g1 = sWgt[n_][1][sp_px];
        float g2 = sWgt[n_][2][sp_px], g3 = sWgt[n_][3][sp_px];
        h8 res;
#pragma unroll
        for (int i = 0; i < 8; i++)
            res[i] = (f16)(g0 * (float)v[0][i] + g1 * (float)v[1][i]
                         + g2 * (float)v[2][i] + g3 * (float)v[3][i]);
        *(h8*)&Xs[sp_px][(sp_oc ^ (sp_px & 7)) * 8] = res;
    };

    auto dmaW = [&](int KC) {
        const f16* src = whb + (size_t)KC * 16384;
#pragma unroll
        for (int i = 0; i < 4; i++) {
            int seg = i * 8 + wv;                        // uniform per wave
            const f16* g = src + seg * 512 + lane * 8;   // 16 B per lane
            f16* l = &Wb[seg * 512];
            __builtin_amdgcn_global_load_lds(
                (const __attribute__((address_space(1))) u32*)g,
                (__attribute__((address_space(3))) u32*)l, 16, 0, 0);
        }
    };

    f4 acc[4][2];
#pragma unroll
    for (int oi = 0; oi < 4; oi++)
#pragma unroll
        for (int pj = 0; pj < 2; pj++) acc[oi][pj] = (f4){0.f, 0.f, 0.f, 0.f};

    dmaW(0);
    {
        h8 v[4];
        gather(0, v);
        commit(0, v);
    }
    __syncthreads();

    for (int kc = 0; kc < NC; kc++) {
        h8 Af[4][2], Bf[2][2];
#pragma unroll
        for (int oi = 0; oi < 4; oi++)
#pragma unroll
            for (int ks = 0; ks < 2; ks++) {
                int rr   = ow * 64 + oi * 16 + col;
                int slot = (ks * 4 + quad) ^ (col & 7);
                Af[oi][ks] = *(const h8*)&Wb[rr * 64 + slot * 8];
            }
#pragma unroll
        for (int pj = 0; pj < 2; pj++)
#pragma unroll
            for (int ks = 0; ks < 2; ks++) {
                int px   = ph * 32 + pj * 16 + col;
                int slot = (ks * 4 + quad) ^ (px & 7);
                Bf[pj][ks] = *(const h8*)&Xs[px][slot * 8];
            }
        h8 gv[4];
        bool more = (kc < NC - 1);
        if (more) gather(kc + 1, gv);         // global reads issued EARLY
        __syncthreads();                      // barrier1: all frag reads done
        if (more) dmaW(kc + 1);               // LDS overwrite now safe
#pragma unroll
        for (int oi = 0; oi < 4; oi++)
#pragma unroll
            for (int pj = 0; pj < 2; pj++) {
                acc[oi][pj] = __builtin_amdgcn_mfma_f32_16x16x32_f16(Af[oi][0], Bf[pj][0], acc[oi][pj], 0, 0, 0);
                acc[oi][pj] = __builtin_amdgcn_mfma_f32_16x16x32_f16(Af[oi][1], Bf[pj][1], acc[oi][pj], 0, 0, 0);
            }
        if (more) commit(kc + 1, gv);         // ds_write after barrier1, pre barrier2
        __syncthreads();                      // barrier2: DMA + commits landed
    }

    // ---- epilogue: frag reg r = gate r for ch = ow*16 + oi*4 + quad ----
#pragma unroll
    for (int oi = 0; oi < 4; oi++) {
        int ch = ow * 16 + oi * 4 + quad;
#pragma unroll
        for (int pj = 0; pj < 2; pj++) {
            int wpos = ph * 32 + pj * 16 + col;
            f4 a = acc[oi][pj];
            float ci  = a[0] + bmS[ch];
            float cf  = a[1] + bmS[64 + ch];
            float co  = a[2] + bmS[128 + ch];
            float cgv = a[3] + bmS[192 + ch];
            float ig  = sigf(ci);
            float fg  = sigf(cf);
            float og_ = sigf(co);
            float gg  = tanhfast(cgv);
            size_t idx = (((size_t)(b * HIDc + ch)) * 64 + h) * 64 + wpos;
            float cp = ccur[idx];
            float cn = fg * cp + ig * gg;
            out[idx] = og_ * tanhfast(cn);                   // h_next
            out[(size_t)Bn * HIDc * HWn + idx] = cn;         // c_next
        }
    }
}

// ---------------------------------------------------------------------------
extern "C" void kernel_launch(void* const* d_in, const int* in_sizes, int n_in,
                              void* d_out, int out_size, void* d_ws, size_t ws_size,
                              hipStream_t stream)
{
    const float* xin  = (const float*)d_in[0];
    const float* hcur = (const float*)d_in[1];
    const float* ccur = (const float*)d_in[2];
    const float* meta = (const float*)d_in[3];
    const float* moff = (const float*)d_in[4];
    const float* w1w  = (const float*)d_in[5];
    const float* w1b  = (const float*)d_in[6];
    const float* w2w  = (const float*)d_in[7];
    const float* w2b  = (const float*)d_in[8];
    const float* blw  = (const float*)d_in[9];
    const float* blb  = (const float*)d_in[10];
    const float* pw   = (const float*)d_in[11];
    const float* pb   = (const float*)d_in[12];
    float* out = (float*)d_out;
    float* bm  = (float*)d_ws;
    f16* f16b  = (f16*)((char*)d_ws + F16_BYTE);
    f16* tx  = f16b + TX_F;
    f16* wh  = f16b + WH_F;
    f16* m1h = f16b + M1H_F;
    f16* m1l = f16b + M1L_F;

    hipLaunchKernelGGL(k_prep, dim3(772), dim3(256), 0, stream,
                       xin, hcur, tx, meta, w1w, w1b, blw, blb, bm, m1h, m1l);
    hipLaunchKernelGGL(k_w2,   dim3(576), dim3(256), 0, stream,
                       w2w, w2b, m1h, m1l, wh);
    hipLaunchKernelGGL(k_main, dim3(256), dim3(512), 0, stream,
                       tx, ccur, moff, pw, pb, bm, wh, out);
}